// Round 10
// baseline (239.057 us; speedup 1.0000x reference)
//
#include <hip/hip_runtime.h>
#include <hip/hip_bf16.h>
#include <math.h>

// Problem constants
#define D_MODEL   768
#define D_INNER   1536
#define D_STATE   128
#define HEADDIM   64
#define NHEADS    24
#define D_CONV    4
#define CONV_DIM  1792            // D_INNER + 2*D_STATE
#define D_IN_PROJ 3352            // 2*D_INNER + 2*D_STATE + NHEADS
#define BATCH     2
#define SEQLEN    2048
#define NROWS     (BATCH*SEQLEN)  // 4096
#define EPS       1e-5f

#define NCHUNK    16
#define CHUNK     128             // SEQLEN / NCHUNK
#define STATE_SZ  (HEADDIM*D_STATE)   // 8192 per (b,h,chunk)

#define N1_PAD    3456            // 27*128, padded N for GEMM1
#define LDST      136             // padded LDS row stride (bf16 elems), 272B
#define H72       72              // padded stride for 64-col half tiles (144B)

typedef __bf16 bf16x8 __attribute__((ext_vector_type(8)));
typedef float  f32x4  __attribute__((ext_vector_type(4)));
typedef short  s16x8  __attribute__((ext_vector_type(8)));

// RNE float -> bf16 bit pattern
__device__ __forceinline__ short f2b(float f) {
    unsigned u = __float_as_uint(f);
    unsigned r = (u + 0x7FFFu + ((u >> 16) & 1u)) >> 16;
    return (short)r;
}
// bf16 bits -> float
__device__ __forceinline__ float b2f(short s) {
    return __uint_as_float(((unsigned)(unsigned short)s) << 16);
}

// ---------------------------------------------------------------------------
// GEMM1: bf16 MFMA, 128x128 tile, 2-phase dbuf (round-7 proven form),
// XCD-swizzled 1D grid, bf16 output via LDS repack (coalesced 16B stores).
// ---------------------------------------------------------------------------
__global__ __launch_bounds__(256) void gemm_bf16_kernel(
    const short* __restrict__ A, const short* __restrict__ W,
    short* __restrict__ C, int K, int Nreal, int NT)
{
    __shared__ short smem[2][2][128][32];   // 32 KB dbuf
    int flat = blockIdx.x;
    int swz  = (flat & 7) * (gridDim.x >> 3) + (flat >> 3);
    const int m0 = (swz / NT) * 128;
    const int n0 = (swz % NT) * 128;
    const int tid  = threadIdx.x;
    const int lane = tid & 63;
    const int wid  = tid >> 6;
    const int wm = wid >> 1, wn = wid & 1;
    const int lr = lane & 15;
    const int kg = lane >> 4;

    f32x4 acc[4][4];
    #pragma unroll
    for (int i = 0; i < 4; ++i)
        #pragma unroll
        for (int j = 0; j < 4; ++j)
            acc[i][j] = (f32x4){0.f, 0.f, 0.f, 0.f};

    const int srow = (lane >> 2);
    const int scol = (lane & 3) * 8;

    auto STAGE = [&](int buf, int k0) {
        #pragma unroll
        for (int it = 0; it < 2; ++it) {
            int r = wid * 32 + it * 16;
            const short* ga = A + (size_t)(m0 + r + srow) * K + k0 + scol;
            const short* gw = W + (size_t)(n0 + r + srow) * K + k0 + scol;
            __builtin_amdgcn_global_load_lds(
                (const __attribute__((address_space(1))) void*)ga,
                (__attribute__((address_space(3))) void*)&smem[buf][0][r][0], 16, 0, 0);
            __builtin_amdgcn_global_load_lds(
                (const __attribute__((address_space(1))) void*)gw,
                (__attribute__((address_space(3))) void*)&smem[buf][1][r][0], 16, 0, 0);
        }
    };
    auto COMPUTE = [&](int buf) {
        bf16x8 af[4], bf[4];
        #pragma unroll
        for (int i = 0; i < 4; ++i)
            af[i] = *(const bf16x8*)&smem[buf][0][wm * 64 + i * 16 + lr][kg * 8];
        #pragma unroll
        for (int j = 0; j < 4; ++j)
            bf[j] = *(const bf16x8*)&smem[buf][1][wn * 64 + j * 16 + lr][kg * 8];
        #pragma unroll
        for (int i = 0; i < 4; ++i)
            #pragma unroll
            for (int j = 0; j < 4; ++j)
                acc[i][j] = __builtin_amdgcn_mfma_f32_16x16x32_bf16(af[i], bf[j], acc[i][j], 0, 0, 0);
    };

    const int nt = K >> 5;
    STAGE(0, 0);
    __syncthreads();
    int cur = 0;
    for (int t = 0; t < nt - 1; ++t) {
        STAGE(cur ^ 1, (t + 1) << 5);
        COMPUTE(cur);
        __syncthreads();
        cur ^= 1;
    }
    COMPUTE(cur);

    __syncthreads();
    short* eb = &smem[0][0][0][0];   // 128 x 128 bf16 repack
    #pragma unroll
    for (int i = 0; i < 4; ++i)
        #pragma unroll
        for (int j = 0; j < 4; ++j)
            #pragma unroll
            for (int r = 0; r < 4; ++r) {
                int row = wm * 64 + i * 16 + kg * 4 + r;
                int col = wn * 64 + j * 16 + lr;
                eb[row * 128 + col] = f2b(acc[i][j][r]);
            }
    __syncthreads();
    #pragma unroll
    for (int ch = 0; ch < 8; ++ch) {
        int cidx = ch * 256 + tid;
        int row  = cidx >> 4;
        int cp   = cidx & 15;
        int ncol = n0 + cp * 8;
        if (ncol < Nreal)
            *(s16x8*)(C + (size_t)(m0 + row) * Nreal + ncol) =
                *(const s16x8*)(eb + row * 128 + cp * 8);
    }
}

// ---------------------------------------------------------------------------
// GEMM2: bf16 MFMA, 128x64 tile, 2-phase dbuf, fp32 out, XCD-swizzled.
// ---------------------------------------------------------------------------
__global__ __launch_bounds__(256) void gemm_bf16_n64_kernel(
    const short* __restrict__ A, const short* __restrict__ W,
    float* __restrict__ C, int K, int N, int NT)
{
    __shared__ short As[2][128][32];
    __shared__ short Ws[2][64][32];
    int flat = blockIdx.x;
    int swz  = (flat & 7) * (gridDim.x >> 3) + (flat >> 3);
    const int m0 = (swz / NT) * 128;
    const int n0 = (swz % NT) * 64;
    const int tid  = threadIdx.x;
    const int lane = tid & 63;
    const int wid  = tid >> 6;
    const int lr = lane & 15;
    const int kg = lane >> 4;

    f32x4 acc[2][4];
    #pragma unroll
    for (int i = 0; i < 2; ++i)
        #pragma unroll
        for (int j = 0; j < 4; ++j)
            acc[i][j] = (f32x4){0.f, 0.f, 0.f, 0.f};

    const int srow = (lane >> 2);
    const int scol = (lane & 3) * 8;

    auto STAGE = [&](int buf, int k0) {
        #pragma unroll
        for (int it = 0; it < 2; ++it) {
            int r = wid * 32 + it * 16;
            const short* ga = A + (size_t)(m0 + r + srow) * K + k0 + scol;
            __builtin_amdgcn_global_load_lds(
                (const __attribute__((address_space(1))) void*)ga,
                (__attribute__((address_space(3))) void*)&As[buf][r][0], 16, 0, 0);
        }
        int r2 = wid * 16;
        const short* gw = W + (size_t)(n0 + r2 + srow) * K + k0 + scol;
        __builtin_amdgcn_global_load_lds(
            (const __attribute__((address_space(1))) void*)gw,
            (__attribute__((address_space(3))) void*)&Ws[buf][r2][0], 16, 0, 0);
    };
    auto COMPUTE = [&](int buf) {
        bf16x8 af[2], bf[4];
        #pragma unroll
        for (int i = 0; i < 2; ++i)
            af[i] = *(const bf16x8*)&As[buf][wid * 32 + i * 16 + lr][kg * 8];
        #pragma unroll
        for (int j = 0; j < 4; ++j)
            bf[j] = *(const bf16x8*)&Ws[buf][j * 16 + lr][kg * 8];
        #pragma unroll
        for (int i = 0; i < 2; ++i)
            #pragma unroll
            for (int j = 0; j < 4; ++j)
                acc[i][j] = __builtin_amdgcn_mfma_f32_16x16x32_bf16(af[i], bf[j], acc[i][j], 0, 0, 0);
    };

    const int nt = K >> 5;
    STAGE(0, 0);
    __syncthreads();
    int cur = 0;
    for (int t = 0; t < nt - 1; ++t) {
        STAGE(cur ^ 1, (t + 1) << 5);
        COMPUTE(cur);
        __syncthreads();
        cur ^= 1;
    }
    COMPUTE(cur);

    #pragma unroll
    for (int i = 0; i < 2; ++i) {
        int mrow = m0 + wid * 32 + i * 16 + kg * 4;
        #pragma unroll
        for (int j = 0; j < 4; ++j) {
            int ncol = n0 + j * 16 + lr;
            #pragma unroll
            for (int r = 0; r < 4; ++r)
                C[(size_t)(mrow + r) * N + ncol] = acc[i][j][r];
        }
    }
}

// ---------------------------------------------------------------------------
// Fused cast kernel: u -> ub, in_proj_w -> padded w1b, out_proj_w -> w2b.
// One launch; segments selected by flat float4-index.
// ---------------------------------------------------------------------------
#define N4_U   (NROWS*D_MODEL/4)          // 786432
#define N4_W1  (N1_PAD*D_MODEL/4)         // 663552
#define N4_W2  (D_MODEL*D_INNER/4)        // 294912
__global__ __launch_bounds__(256) void fused_cast_kernel(
    const float* __restrict__ u, const float* __restrict__ w1,
    const float* __restrict__ w2,
    short* __restrict__ ub, short* __restrict__ w1b, short* __restrict__ w2b)
{
    int i = blockIdx.x * 256 + threadIdx.x;
    const float* src;
    short* dst;
    size_t off;
    if (i < N4_U) {
        src = u; dst = ub; off = (size_t)i * 4;
        float4 v = *(const float4*)(src + off);
        *(short4*)(dst + off) = make_short4(f2b(v.x), f2b(v.y), f2b(v.z), f2b(v.w));
    } else if (i < N4_U + N4_W1) {
        int j = i - N4_U;
        off = (size_t)j * 4;
        int row = (int)(off / D_MODEL);
        float4 v = make_float4(0.f, 0.f, 0.f, 0.f);
        if (row < D_IN_PROJ) v = *(const float4*)(w1 + off);
        *(short4*)(w1b + off) = make_short4(f2b(v.x), f2b(v.y), f2b(v.z), f2b(v.w));
    } else if (i < N4_U + N4_W1 + N4_W2) {
        int j = i - N4_U - N4_W1;
        off = (size_t)j * 4;
        float4 v = *(const float4*)(w2 + off);
        *(short4*)(w2b + off) = make_short4(f2b(v.x), f2b(v.y), f2b(v.z), f2b(v.w));
    }
}

// ---------------------------------------------------------------------------
// Fused depthwise conv (k=4)+bias+SiLU  AND  dt softplus/dtA.
// Blocks [0, CONVB) do conv; blocks [CONVB, CONVB+DTB) do dt.
// ---------------------------------------------------------------------------
#define NG      (CONV_DIM/8)              // 224
#define CONVB   (NROWS*NG/256)            // 3584
#define DTB     (NROWS*NHEADS/256)        // 384
__global__ __launch_bounds__(256) void conv_dt_kernel(
    const short* __restrict__ zxb, short* __restrict__ cob,
    const float* __restrict__ cw, const float* __restrict__ cb,
    const float* __restrict__ dt_bias, const float* __restrict__ A_log,
    float* __restrict__ dtb, float* __restrict__ dta)
{
    if (blockIdx.x < CONVB) {
        int idx = blockIdx.x * 256 + threadIdx.x;
        int g = idx % NG;
        int r = idx / NG;
        int c0 = g * 8;
        int l = r & (SEQLEN - 1);

        float4 w[8];
        #pragma unroll
        for (int e = 0; e < 8; ++e)
            w[e] = *(const float4*)(cw + (size_t)(c0 + e) * 4);

        float acc[8];
        #pragma unroll
        for (int e = 0; e < 8; ++e) acc[e] = cb[c0 + e];

        #pragma unroll
        for (int tap = 0; tap < 4; ++tap) {
            if (l - 3 + tap >= 0) {
                s16x8 v = *(const s16x8*)(zxb + (size_t)(r - 3 + tap) * D_IN_PROJ + D_INNER + c0);
                #pragma unroll
                for (int e = 0; e < 8; ++e) {
                    float we = (tap == 0) ? w[e].x : (tap == 1) ? w[e].y : (tap == 2) ? w[e].z : w[e].w;
                    acc[e] = fmaf(b2f(v[e]), we, acc[e]);
                }
            }
        }
        s16x8 o;
        #pragma unroll
        for (int e = 0; e < 8; ++e)
            o[e] = f2b(acc[e] / (1.f + expf(-acc[e])));
        *(s16x8*)(cob + (size_t)r * CONV_DIM + c0) = o;
    } else {
        int idx = (blockIdx.x - CONVB) * 256 + threadIdx.x;
        int r = idx / NHEADS, h = idx - r * NHEADS;
        float x = b2f(zxb[(size_t)r * D_IN_PROJ + (D_INNER + CONV_DIM) + h]) + dt_bias[h];
        float sp = (x > 20.f) ? x : log1pf(expf(x));
        float A  = -expf(A_log[h]);
        dtb[idx] = sp;
        dta[idx] = sp * A;
    }
}

// ---------------------------------------------------------------------------
// SSD pass A: per (b,h,chunk) chunk-end local state + clg/cumW.
// 768 blocks x 256 threads (4 waves).
// ---------------------------------------------------------------------------
__global__ __launch_bounds__(256) void ssd_states(
    const short* __restrict__ co, const float* __restrict__ dtb,
    const float* __restrict__ dta, float* __restrict__ sstate,
    float* __restrict__ cumW, float* __restrict__ clgbuf)
{
    __shared__ short lds[26112];
    __shared__ float clg[128];
    __shared__ float dts[128];

    int t = blockIdx.x;
    int c = t & 15;
    int hb = t >> 4;
    int h = hb % NHEADS;
    int b = hb / NHEADS;
    const int R0 = b * SEQLEN + c * CHUNK;
    const int tid  = threadIdx.x;
    const int lane = tid & 63;
    const int wid  = tid >> 6;
    const int lr = lane & 15;
    const int kg = lane >> 4;
    const short* cobase = co + (size_t)R0 * CONV_DIM;

    if (tid < 128) {
        clg[tid] = dta[(size_t)(R0 + tid) * NHEADS + h];
        dts[tid] = dtb[(size_t)(R0 + tid) * NHEADS + h];
    }
    __syncthreads();
    for (int off = 1; off < 128; off <<= 1) {
        float v = 0.f;
        if (tid < 128 && tid >= off) v = clg[tid - off];
        __syncthreads();
        if (tid < 128) clg[tid] += v;
        __syncthreads();
    }
    const float clgE = clg[127];
    if (tid < 128) {
        size_t o = ((size_t)(b * NHEADS + h)) * SEQLEN + c * CHUNK + tid;
        cumW[o]   = __expf(clg[tid]);
        clgbuf[o] = clg[tid];
    }

    short* Bt = lds;
    short* Xt = lds + 128 * LDST;
    {
        int r = tid >> 1, q = tid & 1;
        float dtv = dts[r];
        const short* xr = cobase + (size_t)r * CONV_DIM + h * HEADDIM + q * 32;
        #pragma unroll
        for (int i = 0; i < 4; ++i) {
            s16x8 xv = *(const s16x8*)(xr + i * 8);
            #pragma unroll
            for (int e = 0; e < 8; ++e)
                Xt[(q * 32 + i * 8 + e) * LDST + r] = f2b(b2f(xv[e]) * dtv);
        }
        float wstr = __expf(clgE - clg[r]);
        const short* br = cobase + (size_t)r * CONV_DIM + D_INNER + q * 64;
        #pragma unroll
        for (int i = 0; i < 8; ++i) {
            s16x8 bv = *(const s16x8*)(br + i * 8);
            #pragma unroll
            for (int e = 0; e < 8; ++e)
                Bt[(q * 64 + i * 8 + e) * LDST + r] = f2b(b2f(bv[e]) * wstr);
        }
    }
    __syncthreads();

    f32x4 acc[4][2];
    #pragma unroll
    for (int i = 0; i < 4; ++i)
        #pragma unroll
        for (int j = 0; j < 2; ++j)
            acc[i][j] = (f32x4){0.f, 0.f, 0.f, 0.f};
    #pragma unroll
    for (int kk = 0; kk < 4; ++kk) {
        bf16x8 af[4], bf[2];
        #pragma unroll
        for (int i = 0; i < 4; ++i)
            af[i] = *(const bf16x8*)(Xt + (i * 16 + lr) * LDST + kk * 32 + kg * 8);
        #pragma unroll
        for (int j = 0; j < 2; ++j)
            bf[j] = *(const bf16x8*)(Bt + (wid * 32 + j * 16 + lr) * LDST + kk * 32 + kg * 8);
        #pragma unroll
        for (int i = 0; i < 4; ++i)
            #pragma unroll
            for (int j = 0; j < 2; ++j)
                acc[i][j] = __builtin_amdgcn_mfma_f32_16x16x32_bf16(af[i], bf[j], acc[i][j], 0, 0, 0);
    }
    float* sbase = sstate + (((size_t)(b * NHEADS + h)) * NCHUNK + c) * STATE_SZ;
    #pragma unroll
    for (int i = 0; i < 4; ++i)
        #pragma unroll
        for (int j = 0; j < 2; ++j)
            #pragma unroll
            for (int r = 0; r < 4; ++r) {
                int p = i * 16 + kg * 4 + r;
                int n = wid * 32 + j * 16 + lr;
                sbase[p * D_STATE + n] = acc[i][j][r];
            }
}

// ---------------------------------------------------------------------------
// Scan pass: prefix over chunk states per (b,h). In-place, parallel.
// ---------------------------------------------------------------------------
__global__ __launch_bounds__(128) void scan_chunk_prefix(
    const float* __restrict__ cumW, float* __restrict__ sstate)
{
    int blk = blockIdx.x;
    int piece = blk & 15;
    int bh = blk >> 4;
    int tid = threadIdx.x;
    float* base = sstate + (size_t)bh * NCHUNK * STATE_SZ + piece * 512 + tid * 4;
    const float* cw = cumW + (size_t)bh * SEQLEN;
    float4 run = make_float4(0.f, 0.f, 0.f, 0.f);
    for (int c = 0; c < NCHUNK; ++c) {
        float Ac = cw[c * CHUNK + (CHUNK - 1)];
        float* ptr = base + (size_t)c * STATE_SZ;
        float4 loc = *(float4*)ptr;
        *(float4*)ptr = run;
        run.x = fmaf(Ac, run.x, loc.x);
        run.y = fmaf(Ac, run.y, loc.y);
        run.z = fmaf(Ac, run.z, loc.z);
        run.w = fmaf(Ac, run.w, loc.w);
    }
}

// ---------------------------------------------------------------------------
// SSD pass B: full Y per (b,h,chunk). 768 blocks x 512 threads (8 waves).
// Y2 = C.sinit^T is FOLDED into the S-GEMM phase (shared A-operand C, same K):
// per half kh: stage CsH,BsH,SnH; waves do 16 S-MFMAs (wmS,wnS tiling) + 8
// Y2-MFMAs (wm,wn tiling -> accY2 register-local to the combine step).
// ---------------------------------------------------------------------------
__global__ __launch_bounds__(512) void ssd_y(
    const short* __restrict__ co, const float* __restrict__ dtb,
    const float* __restrict__ clgbuf, const float* __restrict__ sstate,
    const float* __restrict__ Dvec, short* __restrict__ ybuf)
{
    __shared__ short lds[26112];
    __shared__ float clg[128];
    __shared__ float dts[128];

    int t = blockIdx.x;
    int c = t & 15;
    int hb = t >> 4;
    int h = hb % NHEADS;
    int b = hb / NHEADS;
    const int R0 = b * SEQLEN + c * CHUNK;
    const int tid  = threadIdx.x;
    const int lane = tid & 63;
    const int wid  = tid >> 6;       // 0..7
    const int lr = lane & 15;
    const int kg = lane >> 4;
    const short* cobase = co + (size_t)R0 * CONV_DIM;

    if (tid < 128) {
        size_t o = ((size_t)(b * NHEADS + h)) * SEQLEN + c * CHUNK + tid;
        clg[tid] = clgbuf[o];
        dts[tid] = dtb[(size_t)(R0 + tid) * NHEADS + h];
    }
    __syncthreads();

    // arena: CsH[128][H72] + BsH[128][H72] + SnH[64][H72] = 23040 shorts
    short* CsH = lds;
    short* BsH = lds + 128 * H72;
    short* SnH = lds + 256 * H72;
    const int wmS = wid >> 2, wnS = wid & 3;   // S tiling: 2x4 waves
    const int wm  = wid >> 1, wn  = wid & 1;   // Y tiling: 4x2 waves
    const float* sinit = sstate + (((size_t)(b * NHEADS + h)) * NCHUNK + c) * STATE_SZ;

    f32x4 accS[4][2];
    f32x4 accY2[2][2];
    #pragma unroll
    for (int i = 0; i < 4; ++i)
        #pragma unroll
        for (int j = 0; j < 2; ++j)
            accS[i][j] = (f32x4){0.f, 0.f, 0.f, 0.f};
    #pragma unroll
    for (int i = 0; i < 2; ++i)
        #pragma unroll
        for (int j = 0; j < 2; ++j)
            accY2[i][j] = (f32x4){0.f, 0.f, 0.f, 0.f};

    for (int kh = 0; kh < 2; ++kh) {
        {   // stage C/B halves (bf16 direct) + sinit half (fp32->bf16)
            int r = tid >> 2, q = tid & 3;
            const short* cr = cobase + (size_t)r * CONV_DIM + (D_INNER + D_STATE) + kh * 64 + q * 16;
            const short* br = cobase + (size_t)r * CONV_DIM + D_INNER + kh * 64 + q * 16;
            *(s16x8*)(CsH + r * H72 + q * 16)     = *(const s16x8*)cr;
            *(s16x8*)(CsH + r * H72 + q * 16 + 8) = *(const s16x8*)(cr + 8);
            *(s16x8*)(BsH + r * H72 + q * 16)     = *(const s16x8*)br;
            *(s16x8*)(BsH + r * H72 + q * 16 + 8) = *(const s16x8*)(br + 8);
            int rp = tid >> 3, qp = tid & 7;     // rp = p 0..63, qp*8 cols
            const float* sr = sinit + (size_t)rp * D_STATE + kh * 64 + qp * 8;
            float4 s0 = *(const float4*)sr;
            float4 s1 = *(const float4*)(sr + 4);
            s16x8 sv;
            sv[0] = f2b(s0.x); sv[1] = f2b(s0.y); sv[2] = f2b(s0.z); sv[3] = f2b(s0.w);
            sv[4] = f2b(s1.x); sv[5] = f2b(s1.y); sv[6] = f2b(s1.z); sv[7] = f2b(s1.w);
            *(s16x8*)(SnH + rp * H72 + qp * 8) = sv;
        }
        __syncthreads();
        #pragma unroll
        for (int kk = 0; kk < 2; ++kk) {
            bf16x8 af[4], bf[2];
            #pragma unroll
            for (int i = 0; i < 4; ++i)
                af[i] = *(const bf16x8*)(CsH + (wmS * 64 + i * 16 + lr) * H72 + kk * 32 + kg * 8);
            #pragma unroll
            for (int j = 0; j < 2; ++j)
                bf[j] = *(const bf16x8*)(BsH + (wnS * 32 + j * 16 + lr) * H72 + kk * 32 + kg * 8);
            #pragma unroll
            for (int i = 0; i < 4; ++i)
                #pragma unroll
                for (int j = 0; j < 2; ++j)
                    accS[i][j] = __builtin_amdgcn_mfma_f32_16x16x32_bf16(af[i], bf[j], accS[i][j], 0, 0, 0);
            // Y2: same A-operand family (C rows in wm tiling), B from SnH
            bf16x8 af2[2], bf2[2];
            #pragma unroll
            for (int i = 0; i < 2; ++i)
                af2[i] = *(const bf16x8*)(CsH + (wm * 32 + i * 16 + lr) * H72 + kk * 32 + kg * 8);
            #pragma unroll
            for (int j = 0; j < 2; ++j)
                bf2[j] = *(const bf16x8*)(SnH + (wn * 32 + j * 16 + lr) * H72 + kk * 32 + kg * 8);
            #pragma unroll
            for (int i = 0; i < 2; ++i)
                #pragma unroll
                for (int j = 0; j < 2; ++j)
                    accY2[i][j] = __builtin_amdgcn_mfma_f32_16x16x32_bf16(af2[i], bf2[j], accY2[i][j], 0, 0, 0);
        }
        __syncthreads();
    }

    // --- Ps = mask/decay(S); stage Xt ---
    short* Ps = lds;                  // [128][LDST]
    short* Xt = lds + 128 * LDST;     // [64][LDST]
    #pragma unroll
    for (int i = 0; i < 4; ++i)
        #pragma unroll
        for (int j = 0; j < 2; ++j)
            #pragma unroll
            for (int r = 0; r < 4; ++r) {
                int l  = wmS * 64 + i * 16 + kg * 4 + r;
                int lp = wnS * 32 + j * 16 + lr;
                float w = (lp <= l) ? __expf(clg[l] - clg[lp]) : 0.f;
                Ps[l * LDST + lp] = f2b(accS[i][j][r] * w);
            }
    if (tid < 256) {
        int r = tid >> 1, q = tid & 1;
        const short* xr = cobase + (size_t)r * CONV_DIM + h * HEADDIM + q * 32;
        float dtv = dts[r];
        #pragma unroll
        for (int i = 0; i < 4; ++i) {
            s16x8 xv = *(const s16x8*)(xr + i * 8);
            #pragma unroll
            for (int e = 0; e < 8; ++e)
                Xt[(q * 32 + i * 8 + e) * LDST + r] = f2b(b2f(xv[e]) * dtv);
        }
    }
    __syncthreads();

    // --- Y1 = Ps . Xt^T ---
    f32x4 acc1[2][2];
    #pragma unroll
    for (int i = 0; i < 2; ++i)
        #pragma unroll
        for (int j = 0; j < 2; ++j)
            acc1[i][j] = (f32x4){0.f, 0.f, 0.f, 0.f};
    #pragma unroll
    for (int kk = 0; kk < 4; ++kk) {
        bf16x8 af[2], bf[2];
        #pragma unroll
        for (int i = 0; i < 2; ++i)
            af[i] = *(const bf16x8*)(Ps + (wm * 32 + i * 16 + lr) * LDST + kk * 32 + kg * 8);
        #pragma unroll
        for (int j = 0; j < 2; ++j)
            bf[j] = *(const bf16x8*)(Xt + (wn * 32 + j * 16 + lr) * LDST + kk * 32 + kg * 8);
        #pragma unroll
        for (int i = 0; i < 2; ++i)
            #pragma unroll
            for (int j = 0; j < 2; ++j)
                acc1[i][j] = __builtin_amdgcn_mfma_f32_16x16x32_bf16(af[i], bf[j], acc1[i][j], 0, 0, 0);
    }
    __syncthreads();

    // --- combine (register-local Y2!) + coalesced bf16 store via LDS ---
    short* yt = lds;                  // [128][H72]
    const float Dh = Dvec[h];
    #pragma unroll
    for (int i = 0; i < 2; ++i)
        #pragma unroll
        for (int j = 0; j < 2; ++j)
            #pragma unroll
            for (int r = 0; r < 4; ++r) {
                int l = wm * 32 + i * 16 + kg * 4 + r;
                int p = wn * 32 + j * 16 + lr;
                float cw = __expf(clg[l]);
                float xval = b2f(cobase[(size_t)l * CONV_DIM + h * HEADDIM + p]);
                yt[l * H72 + p] = f2b(acc1[i][j][r] + cw * accY2[i][j][r] + Dh * xval);
            }
    __syncthreads();
    #pragma unroll
    for (int k = 0; k < 2; ++k) {
        int idx = tid * 2 + k;
        int row = idx >> 3;
        int cp  = idx & 7;
        *(s16x8*)(ybuf + (size_t)(R0 + row) * D_INNER + h * HEADDIM + cp * 8) =
            *(const s16x8*)(yt + row * H72 + cp * 8);
    }
}

// ---------------------------------------------------------------------------
// yz = y * silu(z);  yn = yz * rsqrt(mean(yz^2)+eps) * norm_w  -> bf16
// ---------------------------------------------------------------------------
__global__ __launch_bounds__(192) void gate_norm_kernel(
    const short* __restrict__ zxb, const short* __restrict__ ybuf,
    const float* __restrict__ norm_w, short* __restrict__ yn)
{
    int r = blockIdx.x;
    int c0 = threadIdx.x * 8;
    s16x8 zv = *(const s16x8*)(zxb + (size_t)r * D_IN_PROJ + c0);
    s16x8 yv = *(const s16x8*)(ybuf + (size_t)r * D_INNER + c0);
    float vals[8];
    float ss = 0.f;
    #pragma unroll
    for (int e = 0; e < 8; ++e) {
        float z = b2f(zv[e]);
        float y = b2f(yv[e]);
        float v = y * (z / (1.f + expf(-z)));
        vals[e] = v;
        ss = fmaf(v, v, ss);
    }
    ss += __shfl_xor(ss, 1);
    ss += __shfl_xor(ss, 2);
    ss += __shfl_xor(ss, 4);
    ss += __shfl_xor(ss, 8);
    ss += __shfl_xor(ss, 16);
    ss += __shfl_xor(ss, 32);
    __shared__ float red[3];
    if ((threadIdx.x & 63) == 0) red[threadIdx.x >> 6] = ss;
    __syncthreads();
    float tot = red[0] + red[1] + red[2];
    float scale = rsqrtf(tot / (float)D_INNER + EPS);
    float4 nw0 = *(const float4*)(norm_w + c0);
    float4 nw1 = *(const float4*)(norm_w + c0 + 4);
    const float nw[8] = {nw0.x, nw0.y, nw0.z, nw0.w, nw1.x, nw1.y, nw1.z, nw1.w};
    s16x8 o;
    #pragma unroll
    for (int e = 0; e < 8; ++e)
        o[e] = f2b(vals[e] * scale * nw[e]);
    *(s16x8*)(yn + (size_t)r * D_INNER + c0) = o;
}

// ---------------------------------------------------------------------------
extern "C" void kernel_launch(void* const* d_in, const int* in_sizes, int n_in,
                              void* d_out, int out_size, void* d_ws, size_t ws_size,
                              hipStream_t stream) {
    const float* u          = (const float*)d_in[0];
    const float* in_proj_w  = (const float*)d_in[1];
    const float* conv_w     = (const float*)d_in[2];
    const float* conv_b     = (const float*)d_in[3];
    const float* dt_bias    = (const float*)d_in[4];
    const float* A_log      = (const float*)d_in[5];
    const float* Dvec       = (const float*)d_in[6];
    const float* norm_w     = (const float*)d_in[7];
    const float* out_proj_w = (const float*)d_in[8];
    float* out = (float*)d_out;

    // workspace carve-up:
    short* zxb    = (short*)d_ws;                            // 4096*3352 bf16
    short* cob    = zxb + (size_t)NROWS * D_IN_PROJ;         // 4096*1792 bf16
    float* dtb    = (float*)(cob + (size_t)NROWS * CONV_DIM);
    float* dta    = dtb  + (size_t)NROWS * NHEADS;
    short* ybuf   = (short*)(dta + (size_t)NROWS * NHEADS);  // 4096*1536 bf16
    float* sstate = (float*)(ybuf + (size_t)NROWS * D_INNER);// 48*16*8192 fp32
    float* cumW   = sstate + (size_t)BATCH*NHEADS*NCHUNK*STATE_SZ;
    float* clgbuf = cumW + (size_t)BATCH*NHEADS*SEQLEN;
    short* w2b    = (short*)(clgbuf + (size_t)BATCH*NHEADS*SEQLEN);  // own region (cast early)

    // aliases (regions dead at time of use):
    short* ub  = (short*)sstate;               // 4096*768 (dead before ssd_states)
    short* w1b = ub + (size_t)NROWS * D_MODEL; // 3456*768
    short* ynb = (short*)sstate;               // 4096*1536 (after ssd_y reads sstate)

    // 0) all three casts in one launch
    {
        int total = N4_U + N4_W1 + N4_W2;
        fused_cast_kernel<<<(total + 255)/256, 256, 0, stream>>>(u, in_proj_w, out_proj_w, ub, w1b, w2b);
    }
    // 1) in-proj GEMM (bf16 MFMA, 2-buf dbuf, XCD-swizzled) -> zxb bf16
    gemm_bf16_kernel<<<(NROWS/128)*(N1_PAD/128), 256, 0, stream>>>(ub, w1b, zxb, D_MODEL, D_IN_PROJ, N1_PAD/128);
    // 2) conv+SiLU and dt in one launch
    conv_dt_kernel<<<CONVB + DTB, 256, 0, stream>>>(zxb, cob, conv_w, conv_b, dt_bias, A_log, dtb, dta);
    // 3) SSD: states -> prefix -> Y (Y2 folded into S phase)
    ssd_states<<<BATCH*NHEADS*NCHUNK, 256, 0, stream>>>(cob, dtb, dta, sstate, cumW, clgbuf);
    scan_chunk_prefix<<<BATCH*NHEADS*16, 128, 0, stream>>>(cumW, sstate);
    ssd_y<<<BATCH*NHEADS*NCHUNK, 512, 0, stream>>>(cob, dtb, clgbuf, sstate, Dvec, ybuf);
    // 4) gate + RMSNorm -> bf16
    gate_norm_kernel<<<NROWS, 192, 0, stream>>>(zxb, ybuf, norm_w, ynb);
    // 5) out-proj GEMM (2-buf dbuf, XCD-swizzled) -> fp32 out
    gemm_bf16_n64_kernel<<<(NROWS/128)*(D_MODEL/64), 256, 0, stream>>>(ynb, w2b, out, D_INNER, D_MODEL, D_MODEL/64);
}

// Round 11
// 235.101 us; speedup vs baseline: 1.0168x; 1.0168x over previous
//
#include <hip/hip_runtime.h>
#include <hip/hip_bf16.h>
#include <math.h>

// Problem constants
#define D_MODEL   768
#define D_INNER   1536
#define D_STATE   128
#define HEADDIM   64
#define NHEADS    24
#define D_CONV    4
#define CONV_DIM  1792            // D_INNER + 2*D_STATE
#define D_IN_PROJ 3352            // 2*D_INNER + 2*D_STATE + NHEADS
#define BATCH     2
#define SEQLEN    2048
#define NROWS     (BATCH*SEQLEN)  // 4096
#define EPS       1e-5f

#define NCHUNK    16
#define CHUNK     128             // SEQLEN / NCHUNK
#define STATE_SZ  (HEADDIM*D_STATE)   // 8192 per (b,h,chunk)

#define N1_PAD    3456            // 27*128, padded N for GEMM1
#define LDST      136             // padded LDS row stride (bf16 elems), 272B
#define H72       72              // padded stride for 64-col half tiles (144B)

typedef __bf16 bf16x8 __attribute__((ext_vector_type(8)));
typedef float  f32x4  __attribute__((ext_vector_type(4)));
typedef short  s16x8  __attribute__((ext_vector_type(8)));

// RNE float -> bf16 bit pattern
__device__ __forceinline__ short f2b(float f) {
    unsigned u = __float_as_uint(f);
    unsigned r = (u + 0x7FFFu + ((u >> 16) & 1u)) >> 16;
    return (short)r;
}
// bf16 bits -> float
__device__ __forceinline__ float b2f(short s) {
    return __uint_as_float(((unsigned)(unsigned short)s) << 16);
}

// ---------------------------------------------------------------------------
// GEMM1: bf16 MFMA, 128x128 tile, 2-phase dbuf, XCD-swizzled 1D grid,
// bf16 output via LDS repack (coalesced 16B stores).
// ---------------------------------------------------------------------------
__global__ __launch_bounds__(256) void gemm_bf16_kernel(
    const short* __restrict__ A, const short* __restrict__ W,
    short* __restrict__ C, int K, int Nreal, int NT)
{
    __shared__ short smem[2][2][128][32];   // 32 KB dbuf
    int flat = blockIdx.x;
    int swz  = (flat & 7) * (gridDim.x >> 3) + (flat >> 3);
    const int m0 = (swz / NT) * 128;
    const int n0 = (swz % NT) * 128;
    const int tid  = threadIdx.x;
    const int lane = tid & 63;
    const int wid  = tid >> 6;
    const int wm = wid >> 1, wn = wid & 1;
    const int lr = lane & 15;
    const int kg = lane >> 4;

    f32x4 acc[4][4];
    #pragma unroll
    for (int i = 0; i < 4; ++i)
        #pragma unroll
        for (int j = 0; j < 4; ++j)
            acc[i][j] = (f32x4){0.f, 0.f, 0.f, 0.f};

    const int srow = (lane >> 2);
    const int scol = (lane & 3) * 8;

    auto STAGE = [&](int buf, int k0) {
        #pragma unroll
        for (int it = 0; it < 2; ++it) {
            int r = wid * 32 + it * 16;
            const short* ga = A + (size_t)(m0 + r + srow) * K + k0 + scol;
            const short* gw = W + (size_t)(n0 + r + srow) * K + k0 + scol;
            __builtin_amdgcn_global_load_lds(
                (const __attribute__((address_space(1))) void*)ga,
                (__attribute__((address_space(3))) void*)&smem[buf][0][r][0], 16, 0, 0);
            __builtin_amdgcn_global_load_lds(
                (const __attribute__((address_space(1))) void*)gw,
                (__attribute__((address_space(3))) void*)&smem[buf][1][r][0], 16, 0, 0);
        }
    };
    auto COMPUTE = [&](int buf) {
        bf16x8 af[4], bf[4];
        #pragma unroll
        for (int i = 0; i < 4; ++i)
            af[i] = *(const bf16x8*)&smem[buf][0][wm * 64 + i * 16 + lr][kg * 8];
        #pragma unroll
        for (int j = 0; j < 4; ++j)
            bf[j] = *(const bf16x8*)&smem[buf][1][wn * 64 + j * 16 + lr][kg * 8];
        #pragma unroll
        for (int i = 0; i < 4; ++i)
            #pragma unroll
            for (int j = 0; j < 4; ++j)
                acc[i][j] = __builtin_amdgcn_mfma_f32_16x16x32_bf16(af[i], bf[j], acc[i][j], 0, 0, 0);
    };

    const int nt = K >> 5;
    STAGE(0, 0);
    __syncthreads();
    int cur = 0;
    for (int t = 0; t < nt - 1; ++t) {
        STAGE(cur ^ 1, (t + 1) << 5);
        COMPUTE(cur);
        __syncthreads();
        cur ^= 1;
    }
    COMPUTE(cur);

    __syncthreads();
    short* eb = &smem[0][0][0][0];   // 128 x 128 bf16 repack
    #pragma unroll
    for (int i = 0; i < 4; ++i)
        #pragma unroll
        for (int j = 0; j < 4; ++j)
            #pragma unroll
            for (int r = 0; r < 4; ++r) {
                int row = wm * 64 + i * 16 + kg * 4 + r;
                int col = wn * 64 + j * 16 + lr;
                eb[row * 128 + col] = f2b(acc[i][j][r]);
            }
    __syncthreads();
    #pragma unroll
    for (int ch = 0; ch < 8; ++ch) {
        int cidx = ch * 256 + tid;
        int row  = cidx >> 4;
        int cp   = cidx & 15;
        int ncol = n0 + cp * 8;
        if (ncol < Nreal)
            *(s16x8*)(C + (size_t)(m0 + row) * Nreal + ncol) =
                *(const s16x8*)(eb + row * 128 + cp * 8);
    }
}

// ---------------------------------------------------------------------------
// GEMM2: bf16 MFMA, 128x64 tile, 2-phase dbuf, fp32 out, XCD-swizzled.
// ---------------------------------------------------------------------------
__global__ __launch_bounds__(256) void gemm_bf16_n64_kernel(
    const short* __restrict__ A, const short* __restrict__ W,
    float* __restrict__ C, int K, int N, int NT)
{
    __shared__ short As[2][128][32];
    __shared__ short Ws[2][64][32];
    int flat = blockIdx.x;
    int swz  = (flat & 7) * (gridDim.x >> 3) + (flat >> 3);
    const int m0 = (swz / NT) * 128;
    const int n0 = (swz % NT) * 64;
    const int tid  = threadIdx.x;
    const int lane = tid & 63;
    const int wid  = tid >> 6;
    const int lr = lane & 15;
    const int kg = lane >> 4;

    f32x4 acc[2][4];
    #pragma unroll
    for (int i = 0; i < 2; ++i)
        #pragma unroll
        for (int j = 0; j < 4; ++j)
            acc[i][j] = (f32x4){0.f, 0.f, 0.f, 0.f};

    const int srow = (lane >> 2);
    const int scol = (lane & 3) * 8;

    auto STAGE = [&](int buf, int k0) {
        #pragma unroll
        for (int it = 0; it < 2; ++it) {
            int r = wid * 32 + it * 16;
            const short* ga = A + (size_t)(m0 + r + srow) * K + k0 + scol;
            __builtin_amdgcn_global_load_lds(
                (const __attribute__((address_space(1))) void*)ga,
                (__attribute__((address_space(3))) void*)&As[buf][r][0], 16, 0, 0);
        }
        int r2 = wid * 16;
        const short* gw = W + (size_t)(n0 + r2 + srow) * K + k0 + scol;
        __builtin_amdgcn_global_load_lds(
            (const __attribute__((address_space(1))) void*)gw,
            (__attribute__((address_space(3))) void*)&Ws[buf][r2][0], 16, 0, 0);
    };
    auto COMPUTE = [&](int buf) {
        bf16x8 af[2], bf[4];
        #pragma unroll
        for (int i = 0; i < 2; ++i)
            af[i] = *(const bf16x8*)&As[buf][wid * 32 + i * 16 + lr][kg * 8];
        #pragma unroll
        for (int j = 0; j < 4; ++j)
            bf[j] = *(const bf16x8*)&Ws[buf][j * 16 + lr][kg * 8];
        #pragma unroll
        for (int i = 0; i < 2; ++i)
            #pragma unroll
            for (int j = 0; j < 4; ++j)
                acc[i][j] = __builtin_amdgcn_mfma_f32_16x16x32_bf16(af[i], bf[j], acc[i][j], 0, 0, 0);
    };

    const int nt = K >> 5;
    STAGE(0, 0);
    __syncthreads();
    int cur = 0;
    for (int t = 0; t < nt - 1; ++t) {
        STAGE(cur ^ 1, (t + 1) << 5);
        COMPUTE(cur);
        __syncthreads();
        cur ^= 1;
    }
    COMPUTE(cur);

    #pragma unroll
    for (int i = 0; i < 2; ++i) {
        int mrow = m0 + wid * 32 + i * 16 + kg * 4;
        #pragma unroll
        for (int j = 0; j < 4; ++j) {
            int ncol = n0 + j * 16 + lr;
            #pragma unroll
            for (int r = 0; r < 4; ++r)
                C[(size_t)(mrow + r) * N + ncol] = acc[i][j][r];
        }
    }
}

// ---------------------------------------------------------------------------
// Fused cast kernel: u -> ub, in_proj_w -> padded w1b, out_proj_w -> w2b.
// ---------------------------------------------------------------------------
#define N4_U   (NROWS*D_MODEL/4)
#define N4_W1  (N1_PAD*D_MODEL/4)
#define N4_W2  (D_MODEL*D_INNER/4)
__global__ __launch_bounds__(256) void fused_cast_kernel(
    const float* __restrict__ u, const float* __restrict__ w1,
    const float* __restrict__ w2,
    short* __restrict__ ub, short* __restrict__ w1b, short* __restrict__ w2b)
{
    int i = blockIdx.x * 256 + threadIdx.x;
    size_t off;
    if (i < N4_U) {
        off = (size_t)i * 4;
        float4 v = *(const float4*)(u + off);
        *(short4*)(ub + off) = make_short4(f2b(v.x), f2b(v.y), f2b(v.z), f2b(v.w));
    } else if (i < N4_U + N4_W1) {
        int j = i - N4_U;
        off = (size_t)j * 4;
        int row = (int)(off / D_MODEL);
        float4 v = make_float4(0.f, 0.f, 0.f, 0.f);
        if (row < D_IN_PROJ) v = *(const float4*)(w1 + off);
        *(short4*)(w1b + off) = make_short4(f2b(v.x), f2b(v.y), f2b(v.z), f2b(v.w));
    } else if (i < N4_U + N4_W1 + N4_W2) {
        int j = i - N4_U - N4_W1;
        off = (size_t)j * 4;
        float4 v = *(const float4*)(w2 + off);
        *(short4*)(w2b + off) = make_short4(f2b(v.x), f2b(v.y), f2b(v.z), f2b(v.w));
    }
}

// ---------------------------------------------------------------------------
// Fused depthwise conv (k=4)+bias+SiLU  AND  dt softplus/dtA.
// ---------------------------------------------------------------------------
#define NG      (CONV_DIM/8)              // 224
#define CONVB   (NROWS*NG/256)            // 3584
#define DTB     (NROWS*NHEADS/256)        // 384
__global__ __launch_bounds__(256) void conv_dt_kernel(
    const short* __restrict__ zxb, short* __restrict__ cob,
    const float* __restrict__ cw, const float* __restrict__ cb,
    const float* __restrict__ dt_bias, const float* __restrict__ A_log,
    float* __restrict__ dtb, float* __restrict__ dta)
{
    if (blockIdx.x < CONVB) {
        int idx = blockIdx.x * 256 + threadIdx.x;
        int g = idx % NG;
        int r = idx / NG;
        int c0 = g * 8;
        int l = r & (SEQLEN - 1);

        float4 w[8];
        #pragma unroll
        for (int e = 0; e < 8; ++e)
            w[e] = *(const float4*)(cw + (size_t)(c0 + e) * 4);

        float acc[8];
        #pragma unroll
        for (int e = 0; e < 8; ++e) acc[e] = cb[c0 + e];

        #pragma unroll
        for (int tap = 0; tap < 4; ++tap) {
            if (l - 3 + tap >= 0) {
                s16x8 v = *(const s16x8*)(zxb + (size_t)(r - 3 + tap) * D_IN_PROJ + D_INNER + c0);
                #pragma unroll
                for (int e = 0; e < 8; ++e) {
                    float we = (tap == 0) ? w[e].x : (tap == 1) ? w[e].y : (tap == 2) ? w[e].z : w[e].w;
                    acc[e] = fmaf(b2f(v[e]), we, acc[e]);
                }
            }
        }
        s16x8 o;
        #pragma unroll
        for (int e = 0; e < 8; ++e)
            o[e] = f2b(acc[e] / (1.f + expf(-acc[e])));
        *(s16x8*)(cob + (size_t)r * CONV_DIM + c0) = o;
    } else {
        int idx = (blockIdx.x - CONVB) * 256 + threadIdx.x;
        int r = idx / NHEADS, h = idx - r * NHEADS;
        float x = b2f(zxb[(size_t)r * D_IN_PROJ + (D_INNER + CONV_DIM) + h]) + dt_bias[h];
        float sp = (x > 20.f) ? x : log1pf(expf(x));
        float A  = -expf(A_log[h]);
        dtb[idx] = sp;
        dta[idx] = sp * A;
    }
}

// ---------------------------------------------------------------------------
// SSD pass A: per (b,h,chunk) chunk-end local state (bf16) + clg/cumWend.
// 768 blocks x 512 threads (8 waves). Staging spread over all 512 threads;
// epilogue repacks state through LDS for coalesced bf16 stores.
// ---------------------------------------------------------------------------
__global__ __launch_bounds__(512) void ssd_states(
    const short* __restrict__ co, const float* __restrict__ dtb,
    const float* __restrict__ dta, short* __restrict__ sstate,
    float* __restrict__ cumWend, float* __restrict__ clgbuf)
{
    __shared__ short lds[26112];      // Bt[128][136]=17408 + Xt[64][136]=8704
    __shared__ float clg[128];
    __shared__ float dts[128];

    int t = blockIdx.x;
    int c = t & 15;
    int hb = t >> 4;
    int h = hb % NHEADS;
    int b = hb / NHEADS;
    const int R0 = b * SEQLEN + c * CHUNK;
    const int tid  = threadIdx.x;
    const int lane = tid & 63;
    const int wid  = tid >> 6;       // 0..7
    const int lr = lane & 15;
    const int kg = lane >> 4;
    const short* cobase = co + (size_t)R0 * CONV_DIM;

    if (tid < 128) {
        clg[tid] = dta[(size_t)(R0 + tid) * NHEADS + h];
        dts[tid] = dtb[(size_t)(R0 + tid) * NHEADS + h];
    }
    __syncthreads();
    for (int off = 1; off < 128; off <<= 1) {
        float v = 0.f;
        if (tid < 128 && tid >= off) v = clg[tid - off];
        __syncthreads();
        if (tid < 128) clg[tid] += v;
        __syncthreads();
    }
    const float clgE = clg[127];
    if (tid < 128)
        clgbuf[((size_t)(b * NHEADS + h)) * SEQLEN + c * CHUNK + tid] = clg[tid];
    if (tid == 127)
        cumWend[(b * NHEADS + h) * NCHUNK + c] = __expf(clgE);

    // stage Xt[p][l] = dt_l*x[l][p]; Bt[n][l] = exp(clgE-clg[l])*B[l][n]
    short* Bt = lds;                  // [128][LDST]
    short* Xt = lds + 128 * LDST;     // [64][LDST]
    {
        int r = tid >> 2, q = tid & 3;   // r = l 0..127; q = quarter
        float dtv  = dts[r];
        float wstr = __expf(clgE - clg[r]);
        const short* xr = cobase + (size_t)r * CONV_DIM + h * HEADDIM + q * 16;
        s16x8 xv0 = *(const s16x8*)xr;
        s16x8 xv1 = *(const s16x8*)(xr + 8);
        #pragma unroll
        for (int e = 0; e < 8; ++e) {
            Xt[(q * 16 + e) * LDST + r]     = f2b(b2f(xv0[e]) * dtv);
            Xt[(q * 16 + 8 + e) * LDST + r] = f2b(b2f(xv1[e]) * dtv);
        }
        const short* br = cobase + (size_t)r * CONV_DIM + D_INNER + q * 32;
        #pragma unroll
        for (int i = 0; i < 4; ++i) {
            s16x8 bv = *(const s16x8*)(br + i * 8);
            #pragma unroll
            for (int e = 0; e < 8; ++e)
                Bt[(q * 32 + i * 8 + e) * LDST + r] = f2b(b2f(bv[e]) * wstr);
        }
    }
    __syncthreads();

    // state GEMM: M=64 (p), N=128 (n), K=128 (l). 8 waves, n-strip wid*16.
    f32x4 acc[4];
    #pragma unroll
    for (int i = 0; i < 4; ++i) acc[i] = (f32x4){0.f, 0.f, 0.f, 0.f};
    #pragma unroll
    for (int kk = 0; kk < 4; ++kk) {
        bf16x8 af[4], bf;
        #pragma unroll
        for (int i = 0; i < 4; ++i)
            af[i] = *(const bf16x8*)(Xt + (i * 16 + lr) * LDST + kk * 32 + kg * 8);
        bf = *(const bf16x8*)(Bt + (wid * 16 + lr) * LDST + kk * 32 + kg * 8);
        #pragma unroll
        for (int i = 0; i < 4; ++i)
            acc[i] = __builtin_amdgcn_mfma_f32_16x16x32_bf16(af[i], bf, acc[i], 0, 0, 0);
    }
    __syncthreads();

    // repack bf16 state through LDS, then coalesced 16B stores
    short* yt2 = lds;                 // [64][LDST]
    #pragma unroll
    for (int i = 0; i < 4; ++i)
        #pragma unroll
        for (int r = 0; r < 4; ++r) {
            int p = i * 16 + kg * 4 + r;
            int n = wid * 16 + lr;
            yt2[p * LDST + n] = f2b(acc[i][r]);
        }
    __syncthreads();
    short* sbase = sstate + (((size_t)(b * NHEADS + h)) * NCHUNK + c) * STATE_SZ;
    #pragma unroll
    for (int k = 0; k < 2; ++k) {
        int idx = tid * 2 + k;           // 0..1023 = 64 rows x 16 chunks
        int row = idx >> 4;
        int cp  = idx & 15;
        *(s16x8*)(sbase + row * D_STATE + cp * 8) =
            *(const s16x8*)(yt2 + row * LDST + cp * 8);
    }
}

// ---------------------------------------------------------------------------
// Scan pass: prefix over chunk states per (b,h). bf16 storage, fp32 running.
// grid = 48 bh x 8 pieces = 384 blocks x 128 threads x 8 elems.
// ---------------------------------------------------------------------------
__global__ __launch_bounds__(128) void scan_chunk_prefix(
    const float* __restrict__ cumWend, short* __restrict__ sstate)
{
    int blk = blockIdx.x;
    int piece = blk & 7;
    int bh = blk >> 3;
    int tid = threadIdx.x;
    short* base = sstate + (size_t)bh * NCHUNK * STATE_SZ + piece * 1024 + tid * 8;
    const float* cw = cumWend + (size_t)bh * NCHUNK;
    float run[8];
    #pragma unroll
    for (int e = 0; e < 8; ++e) run[e] = 0.f;
    for (int c = 0; c < NCHUNK; ++c) {
        float Ac = cw[c];
        short* ptr = base + (size_t)c * STATE_SZ;
        s16x8 loc = *(s16x8*)ptr;
        s16x8 st;
        #pragma unroll
        for (int e = 0; e < 8; ++e) st[e] = f2b(run[e]);
        *(s16x8*)ptr = st;
        #pragma unroll
        for (int e = 0; e < 8; ++e)
            run[e] = fmaf(Ac, run[e], b2f(loc[e]));
    }
}

// ---------------------------------------------------------------------------
// SSD pass B: full Y per (b,h,chunk). 768 blocks x 512 threads (8 waves).
// Y2 = C.sinit^T folded into the S-GEMM phase; sinit staged directly (bf16).
// ---------------------------------------------------------------------------
__global__ __launch_bounds__(512) void ssd_y(
    const short* __restrict__ co, const float* __restrict__ dtb,
    const float* __restrict__ clgbuf, const short* __restrict__ sstate,
    const float* __restrict__ Dvec, short* __restrict__ ybuf)
{
    __shared__ short lds[26112];
    __shared__ float clg[128];
    __shared__ float dts[128];

    int t = blockIdx.x;
    int c = t & 15;
    int hb = t >> 4;
    int h = hb % NHEADS;
    int b = hb / NHEADS;
    const int R0 = b * SEQLEN + c * CHUNK;
    const int tid  = threadIdx.x;
    const int lane = tid & 63;
    const int wid  = tid >> 6;       // 0..7
    const int lr = lane & 15;
    const int kg = lane >> 4;
    const short* cobase = co + (size_t)R0 * CONV_DIM;

    if (tid < 128) {
        size_t o = ((size_t)(b * NHEADS + h)) * SEQLEN + c * CHUNK + tid;
        clg[tid] = clgbuf[o];
        dts[tid] = dtb[(size_t)(R0 + tid) * NHEADS + h];
    }
    __syncthreads();

    // arena: CsH[128][H72] + BsH[128][H72] + SnH[64][H72] = 23040 shorts
    short* CsH = lds;
    short* BsH = lds + 128 * H72;
    short* SnH = lds + 256 * H72;
    const int wmS = wid >> 2, wnS = wid & 3;   // S tiling: 2x4 waves
    const int wm  = wid >> 1, wn  = wid & 1;   // Y tiling: 4x2 waves
    const short* sinit = sstate + (((size_t)(b * NHEADS + h)) * NCHUNK + c) * STATE_SZ;

    f32x4 accS[4][2];
    f32x4 accY2[2][2];
    #pragma unroll
    for (int i = 0; i < 4; ++i)
        #pragma unroll
        for (int j = 0; j < 2; ++j)
            accS[i][j] = (f32x4){0.f, 0.f, 0.f, 0.f};
    #pragma unroll
    for (int i = 0; i < 2; ++i)
        #pragma unroll
        for (int j = 0; j < 2; ++j)
            accY2[i][j] = (f32x4){0.f, 0.f, 0.f, 0.f};

    for (int kh = 0; kh < 2; ++kh) {
        {   // stage C/B halves + sinit half (all bf16 direct copies)
            int r = tid >> 2, q = tid & 3;
            const short* cr = cobase + (size_t)r * CONV_DIM + (D_INNER + D_STATE) + kh * 64 + q * 16;
            const short* br = cobase + (size_t)r * CONV_DIM + D_INNER + kh * 64 + q * 16;
            *(s16x8*)(CsH + r * H72 + q * 16)     = *(const s16x8*)cr;
            *(s16x8*)(CsH + r * H72 + q * 16 + 8) = *(const s16x8*)(cr + 8);
            *(s16x8*)(BsH + r * H72 + q * 16)     = *(const s16x8*)br;
            *(s16x8*)(BsH + r * H72 + q * 16 + 8) = *(const s16x8*)(br + 8);
            int rp = tid >> 3, qp = tid & 7;
            *(s16x8*)(SnH + rp * H72 + qp * 8) =
                *(const s16x8*)(sinit + (size_t)rp * D_STATE + kh * 64 + qp * 8);
        }
        __syncthreads();
        #pragma unroll
        for (int kk = 0; kk < 2; ++kk) {
            bf16x8 af[4], bf[2];
            #pragma unroll
            for (int i = 0; i < 4; ++i)
                af[i] = *(const bf16x8*)(CsH + (wmS * 64 + i * 16 + lr) * H72 + kk * 32 + kg * 8);
            #pragma unroll
            for (int j = 0; j < 2; ++j)
                bf[j] = *(const bf16x8*)(BsH + (wnS * 32 + j * 16 + lr) * H72 + kk * 32 + kg * 8);
            #pragma unroll
            for (int i = 0; i < 4; ++i)
                #pragma unroll
                for (int j = 0; j < 2; ++j)
                    accS[i][j] = __builtin_amdgcn_mfma_f32_16x16x32_bf16(af[i], bf[j], accS[i][j], 0, 0, 0);
            bf16x8 af2[2], bf2[2];
            #pragma unroll
            for (int i = 0; i < 2; ++i)
                af2[i] = *(const bf16x8*)(CsH + (wm * 32 + i * 16 + lr) * H72 + kk * 32 + kg * 8);
            #pragma unroll
            for (int j = 0; j < 2; ++j)
                bf2[j] = *(const bf16x8*)(SnH + (wn * 32 + j * 16 + lr) * H72 + kk * 32 + kg * 8);
            #pragma unroll
            for (int i = 0; i < 2; ++i)
                #pragma unroll
                for (int j = 0; j < 2; ++j)
                    accY2[i][j] = __builtin_amdgcn_mfma_f32_16x16x32_bf16(af2[i], bf2[j], accY2[i][j], 0, 0, 0);
        }
        __syncthreads();
    }

    // --- Ps = mask/decay(S); stage Xt ---
    short* Ps = lds;                  // [128][LDST]
    short* Xt = lds + 128 * LDST;     // [64][LDST]
    #pragma unroll
    for (int i = 0; i < 4; ++i)
        #pragma unroll
        for (int j = 0; j < 2; ++j)
            #pragma unroll
            for (int r = 0; r < 4; ++r) {
                int l  = wmS * 64 + i * 16 + kg * 4 + r;
                int lp = wnS * 32 + j * 16 + lr;
                float w = (lp <= l) ? __expf(clg[l] - clg[lp]) : 0.f;
                Ps[l * LDST + lp] = f2b(accS[i][j][r] * w);
            }
    if (tid < 256) {
        int r = tid >> 1, q = tid & 1;
        const short* xr = cobase + (size_t)r * CONV_DIM + h * HEADDIM + q * 32;
        float dtv = dts[r];
        #pragma unroll
        for (int i = 0; i < 4; ++i) {
            s16x8 xv = *(const s16x8*)(xr + i * 8);
            #pragma unroll
            for (int e = 0; e < 8; ++e)
                Xt[(q * 32 + i * 8 + e) * LDST + r] = f2b(b2f(xv[e]) * dtv);
        }
    }
    __syncthreads();

    // --- Y1 = Ps . Xt^T ---
    f32x4 acc1[2][2];
    #pragma unroll
    for (int i = 0; i < 2; ++i)
        #pragma unroll
        for (int j = 0; j < 2; ++j)
            acc1[i][j] = (f32x4){0.f, 0.f, 0.f, 0.f};
    #pragma unroll
    for (int kk = 0; kk < 4; ++kk) {
        bf16x8 af[2], bf[2];
        #pragma unroll
        for (int i = 0; i < 2; ++i)
            af[i] = *(const bf16x8*)(Ps + (wm * 32 + i * 16 + lr) * LDST + kk * 32 + kg * 8);
        #pragma unroll
        for (int j = 0; j < 2; ++j)
            bf[j] = *(const bf16x8*)(Xt + (wn * 32 + j * 16 + lr) * LDST + kk * 32 + kg * 8);
        #pragma unroll
        for (int i = 0; i < 2; ++i)
            #pragma unroll
            for (int j = 0; j < 2; ++j)
                acc1[i][j] = __builtin_amdgcn_mfma_f32_16x16x32_bf16(af[i], bf[j], acc1[i][j], 0, 0, 0);
    }
    __syncthreads();

    // --- combine + coalesced bf16 store via LDS ---
    short* yt = lds;                  // [128][H72]
    const float Dh = Dvec[h];
    #pragma unroll
    for (int i = 0; i < 2; ++i)
        #pragma unroll
        for (int j = 0; j < 2; ++j)
            #pragma unroll
            for (int r = 0; r < 4; ++r) {
                int l = wm * 32 + i * 16 + kg * 4 + r;
                int p = wn * 32 + j * 16 + lr;
                float cw = __expf(clg[l]);
                float xval = b2f(cobase[(size_t)l * CONV_DIM + h * HEADDIM + p]);
                yt[l * H72 + p] = f2b(acc1[i][j][r] + cw * accY2[i][j][r] + Dh * xval);
            }
    __syncthreads();
    #pragma unroll
    for (int k = 0; k < 2; ++k) {
        int idx = tid * 2 + k;
        int row = idx >> 3;
        int cp  = idx & 7;
        *(s16x8*)(ybuf + (size_t)(R0 + row) * D_INNER + h * HEADDIM + cp * 8) =
            *(const s16x8*)(yt + row * H72 + cp * 8);
    }
}

// ---------------------------------------------------------------------------
// yz = y * silu(z);  yn = yz * rsqrt(mean(yz^2)+eps) * norm_w  -> bf16
// ---------------------------------------------------------------------------
__global__ __launch_bounds__(192) void gate_norm_kernel(
    const short* __restrict__ zxb, const short* __restrict__ ybuf,
    const float* __restrict__ norm_w, short* __restrict__ yn)
{
    int r = blockIdx.x;
    int c0 = threadIdx.x * 8;
    s16x8 zv = *(const s16x8*)(zxb + (size_t)r * D_IN_PROJ + c0);
    s16x8 yv = *(const s16x8*)(ybuf + (size_t)r * D_INNER + c0);
    float vals[8];
    float ss = 0.f;
    #pragma unroll
    for (int e = 0; e < 8; ++e) {
        float z = b2f(zv[e]);
        float y = b2f(yv[e]);
        float v = y * (z / (1.f + expf(-z)));
        vals[e] = v;
        ss = fmaf(v, v, ss);
    }
    ss += __shfl_xor(ss, 1);
    ss += __shfl_xor(ss, 2);
    ss += __shfl_xor(ss, 4);
    ss += __shfl_xor(ss, 8);
    ss += __shfl_xor(ss, 16);
    ss += __shfl_xor(ss, 32);
    __shared__ float red[3];
    if ((threadIdx.x & 63) == 0) red[threadIdx.x >> 6] = ss;
    __syncthreads();
    float tot = red[0] + red[1] + red[2];
    float scale = rsqrtf(tot / (float)D_INNER + EPS);
    float4 nw0 = *(const float4*)(norm_w + c0);
    float4 nw1 = *(const float4*)(norm_w + c0 + 4);
    const float nw[8] = {nw0.x, nw0.y, nw0.z, nw0.w, nw1.x, nw1.y, nw1.z, nw1.w};
    s16x8 o;
    #pragma unroll
    for (int e = 0; e < 8; ++e)
        o[e] = f2b(vals[e] * scale * nw[e]);
    *(s16x8*)(yn + (size_t)r * D_INNER + c0) = o;
}

// ---------------------------------------------------------------------------
extern "C" void kernel_launch(void* const* d_in, const int* in_sizes, int n_in,
                              void* d_out, int out_size, void* d_ws, size_t ws_size,
                              hipStream_t stream) {
    const float* u          = (const float*)d_in[0];
    const float* in_proj_w  = (const float*)d_in[1];
    const float* conv_w     = (const float*)d_in[2];
    const float* conv_b     = (const float*)d_in[3];
    const float* dt_bias    = (const float*)d_in[4];
    const float* A_log      = (const float*)d_in[5];
    const float* Dvec       = (const float*)d_in[6];
    const float* norm_w     = (const float*)d_in[7];
    const float* out_proj_w = (const float*)d_in[8];
    float* out = (float*)d_out;

    // workspace carve-up:
    short* zxb    = (short*)d_ws;                            // 4096*3352 bf16
    short* cob    = zxb + (size_t)NROWS * D_IN_PROJ;         // 4096*1792 bf16
    float* dtb    = (float*)(cob + (size_t)NROWS * CONV_DIM);
    float* dta    = dtb  + (size_t)NROWS * NHEADS;
    short* ybuf   = (short*)(dta + (size_t)NROWS * NHEADS);  // 4096*1536 bf16
    short* sstate = ybuf + (size_t)NROWS * D_INNER;          // 48*16*8192 bf16
    float* cumWend= (float*)(sstate + (size_t)BATCH*NHEADS*NCHUNK*STATE_SZ); // 768
    float* clgbuf = cumWend + BATCH*NHEADS*NCHUNK;
    short* w2b    = (short*)(clgbuf + (size_t)BATCH*NHEADS*SEQLEN);

    // aliases (regions dead at time of use):
    short* ub  = sstate;                       // 4096*768 (dead before ssd_states)
    short* w1b = ub + (size_t)NROWS * D_MODEL; // 3456*768 (fits: 5.8M <= 6.29M)
    short* ynb = sstate;                       // 4096*1536 (after ssd_y reads sstate)

    // 0) all three casts in one launch
    {
        int total = N4_U + N4_W1 + N4_W2;
        fused_cast_kernel<<<(total + 255)/256, 256, 0, stream>>>(u, in_proj_w, out_proj_w, ub, w1b, w2b);
    }
    // 1) in-proj GEMM (bf16 MFMA, 2-buf dbuf, XCD-swizzled) -> zxb bf16
    gemm_bf16_kernel<<<(NROWS/128)*(N1_PAD/128), 256, 0, stream>>>(ub, w1b, zxb, D_MODEL, D_IN_PROJ, N1_PAD/128);
    // 2) conv+SiLU and dt in one launch
    conv_dt_kernel<<<CONVB + DTB, 256, 0, stream>>>(zxb, cob, conv_w, conv_b, dt_bias, A_log, dtb, dta);
    // 3) SSD: states (bf16) -> prefix (bf16) -> Y
    ssd_states<<<BATCH*NHEADS*NCHUNK, 512, 0, stream>>>(cob, dtb, dta, sstate, cumWend, clgbuf);
    scan_chunk_prefix<<<BATCH*NHEADS*8, 128, 0, stream>>>(cumWend, sstate);
    ssd_y<<<BATCH*NHEADS*NCHUNK, 512, 0, stream>>>(cob, dtb, clgbuf, sstate, Dvec, ybuf);
    // 4) gate + RMSNorm -> bf16
    gate_norm_kernel<<<NROWS, 192, 0, stream>>>(zxb, ybuf, norm_w, ynb);
    // 5) out-proj GEMM (2-buf dbuf, XCD-swizzled) -> fp32 out
    gemm_bf16_n64_kernel<<<(NROWS/128)*(D_MODEL/64), 256, 0, stream>>>(ynb, w2b, out, D_INNER, D_MODEL, D_MODEL/64);
}